// Round 7
// baseline (2055.372 us; speedup 1.0000x reference)
//
#include <hip/hip_runtime.h>
#include <hip/hip_bf16.h>
#include <hip/hip_fp16.h>
#include <type_traits>

#define N_NODES 50000
#define N_EDGES 600000
#define H 128

// ---------------- workspace layout (word offsets), ea LAST and sized at runtime --------
// h0  : [0, 6,400,000)
// h1  : [6,400,000, 12,800,000)
// row_ptr (int, N+1): [12,800,000, 12,850,001)
// cursor  (int, N)  : [12,850,004, 12,900,004)
// col_e   (int, E)  : [12,900,004, 13,500,004)
// col_s   (int, E)  : [13,500,004, 14,100,004)
// ea  : 14,100,004 .. +76.8M words (fp32) or +38.4M words (fp16)
constexpr size_t W_H1  = 6400000;
constexpr size_t W_RP  = 12800000;
constexpr size_t W_CUR = 12850004;
constexpr size_t W_CE  = 12900004;
constexpr size_t W_CS  = 13500004;
constexpr size_t W_EA  = 14100004;                       // *4B = 56,400,016 (16B aligned)
constexpr size_t NEED32 = (W_EA + (size_t)N_EDGES * H) * 4;        // 363,600,016 B
constexpr size_t NEED16 = (W_EA + (size_t)N_EDGES * H / 2) * 4;    // 210,000,016 B

// ---------------- CSR build ----------------
__global__ void count_kernel(const int* __restrict__ ei, int* __restrict__ cnt) {
    int e = blockIdx.x * blockDim.x + threadIdx.x;
    if (e < N_EDGES) atomicAdd(&cnt[ei[N_EDGES + e]], 1);
}

// 1024-thread single-block scan: wave-level __shfl_up scan + cross-wave LDS scan.
__global__ void scan_kernel(int* __restrict__ cursor, int* __restrict__ row_ptr) {
    __shared__ int wsum[16];
    __shared__ int wexc[16];
    __shared__ int s_total;
    const int t = threadIdx.x;
    const int lane = t & 63, wid = t >> 6;
    int carry = 0;
    if (t == 0) row_ptr[0] = 0;
    for (int base = 0; base < N_NODES; base += 1024) {
        int i = base + t;
        int v = (i < N_NODES) ? cursor[i] : 0;
        int x = v;
#pragma unroll
        for (int off = 1; off < 64; off <<= 1) {
            int y = __shfl_up(x, off, 64);
            if (lane >= off) x += y;
        }
        if (lane == 63) wsum[wid] = x;
        __syncthreads();
        if (wid == 0 && lane < 16) {
            int w = wsum[lane];
            int xs = w;
#pragma unroll
            for (int off = 1; off < 16; off <<= 1) {
                int y = __shfl_up(xs, off, 64);
                if (lane >= off) xs += y;
            }
            wexc[lane] = xs - w;          // exclusive cross-wave prefix
            if (lane == 15) s_total = xs; // pass total
        }
        __syncthreads();
        int incl = carry + wexc[wid] + x; // inclusive global prefix
        if (i < N_NODES) {
            cursor[i] = incl - v;         // exclusive -> running cursor
            row_ptr[i + 1] = incl;
        }
        carry += s_total;
        __syncthreads(); // protect wsum/s_total before next pass overwrites
    }
}

__global__ void fill_kernel(const int* __restrict__ ei, int* __restrict__ cursor,
                            int* __restrict__ col_e, int* __restrict__ col_s) {
    int e = blockIdx.x * blockDim.x + threadIdx.x;
    if (e < N_EDGES) {
        int d = ei[N_EDGES + e];
        int pos = atomicAdd(&cursor[d], 1);
        col_e[pos] = e;
        col_s[pos] = ei[e];
    }
}

// ---------------- shared GEMM core: 32 rows x 128 cols, 256 threads ----------------
// a_lds: [32][128] row-major tile, w_lds: [128][128] row-major.
// thread (tx = t&31, ty = t>>5) computes rows ty*4..+3, cols tx*4..+3.
__device__ __forceinline__ void mm_tile(const float* __restrict__ a_lds,
                                        const float* __restrict__ w_lds,
                                        int tx, int ty, float acc[4][4]) {
#pragma unroll 8
    for (int k = 0; k < H; k += 4) {
        float4 av[4], wv[4];
#pragma unroll
        for (int rr = 0; rr < 4; ++rr)
            av[rr] = *(const float4*)&a_lds[(ty * 4 + rr) * H + k];
#pragma unroll
        for (int kk = 0; kk < 4; ++kk)
            wv[kk] = *(const float4*)&w_lds[(k + kk) * H + tx * 4];
#pragma unroll
        for (int rr = 0; rr < 4; ++rr) {
#pragma unroll
            for (int kk = 0; kk < 4; ++kk) {
                float a = ((const float*)&av[rr])[kk];
                acc[rr][0] = fmaf(a, ((const float*)&wv[kk])[0], acc[rr][0]);
                acc[rr][1] = fmaf(a, ((const float*)&wv[kk])[1], acc[rr][1]);
                acc[rr][2] = fmaf(a, ((const float*)&wv[kk])[2], acc[rr][2]);
                acc[rr][3] = fmaf(a, ((const float*)&wv[kk])[3], acc[rr][3]);
            }
        }
    }
}

// LayerNorm over one row spread across a 32-lane tx group (4 vals/lane).
// xor masks 1..16 keep lanes within their 32-lane half; call UNCONDITIONALLY.
__device__ __forceinline__ float4 ln_vals(float v0, float v1, float v2, float v3,
                                          int tx, const float* __restrict__ g,
                                          const float* __restrict__ be) {
    float sum = v0 + v1 + v2 + v3;
    float sq = v0 * v0 + v1 * v1 + v2 * v2 + v3 * v3;
#pragma unroll
    for (int m = 1; m < 32; m <<= 1) {
        sum += __shfl_xor(sum, m, 64);
        sq  += __shfl_xor(sq, m, 64);
    }
    float mean = sum * 0.0078125f;
    float var = sq * 0.0078125f - mean * mean;
    float rstd = rsqrtf(var + 1e-5f);
    float4 gv = *(const float4*)&g[tx * 4];
    float4 bv = *(const float4*)&be[tx * 4];
    float4 o;
    o.x = (v0 - mean) * rstd * gv.x + bv.x;
    o.y = (v1 - mean) * rstd * gv.y + bv.y;
    o.z = (v2 - mean) * rstd * gv.z + bv.z;
    o.w = (v3 - mean) * rstd * gv.w + bv.w;
    return o;
}

// ---------------- encoder: OUT = LN(relu(in@w1+b1)@w2+b2), OUT_T = float or __half ----
template <int IN_DIM, typename OUT_T>
__global__ __launch_bounds__(256) void encoder_kernel(
    const float* __restrict__ in, const float* __restrict__ w1,
    const float* __restrict__ b1, const float* __restrict__ w2,
    const float* __restrict__ b2, const float* __restrict__ g,
    const float* __restrict__ be, OUT_T* __restrict__ out,
    int nrows) {
    __shared__ float w_lds[H * H];
    __shared__ float a_lds[32 * H];
    const int t = threadIdx.x;
    const int row0 = blockIdx.x * 32;

#pragma unroll
    for (int i = 0; i < 16; ++i)
        *(float4*)&w_lds[t * 4 + i * 1024] = *(const float4*)&w2[t * 4 + i * 1024];

    // hidden stage: column-per-thread (conflict-free LDS writes)
    {
        const int c = t & 127;
        const int rh = (t >> 7) * 16;
        const float bb1 = b1[c];
        float w1r[IN_DIM];
#pragma unroll
        for (int i = 0; i < IN_DIM; ++i)
            w1r[i] = w1[i * H + c];
#pragma unroll 4
        for (int rr = 0; rr < 16; ++rr) {
            int r = rh + rr;
            int grow = row0 + r;
            float acc = bb1;
            if (grow < nrows) {
#pragma unroll
                for (int i = 0; i < IN_DIM; ++i)
                    acc = fmaf(in[(size_t)grow * IN_DIM + i], w1r[i], acc);
            }
            a_lds[r * H + c] = fmaxf(acc, 0.f);
        }
    }
    __syncthreads();

    const int tx = t & 31, ty = t >> 5;
    float acc[4][4] = {};
    mm_tile(a_lds, w_lds, tx, ty, acc);

    float4 bb = *(const float4*)&b2[tx * 4];
#pragma unroll
    for (int rr = 0; rr < 4; ++rr) {
        int gr = row0 + ty * 4 + rr;
        float4 o = ln_vals(acc[rr][0] + bb.x, acc[rr][1] + bb.y,
                           acc[rr][2] + bb.z, acc[rr][3] + bb.w, tx, g, be);
        if (gr < nrows) {
            if constexpr (std::is_same<OUT_T, float>::value) {
                *(float4*)(out + (size_t)gr * H + tx * 4) = o;
            } else {
                __half2* dp = (__half2*)(out + (size_t)gr * H + tx * 4);
                dp[0] = __floats2half2_rn(o.x, o.y);
                dp[1] = __floats2half2_rn(o.z, o.w);
            }
        }
    }
}

// ---------------- fused GINEConv layer ----------------
// a = h_in + sum_in relu(h_in[src]+ea[e]);  hid = relu(a@w1+b1)  (kept in LDS)
// h_out = LN(h_in + relu(hid@w2+b2))
template <typename EA_T>
__global__ __launch_bounds__(256) void conv_kernel(
    const float* __restrict__ h_in, const EA_T* __restrict__ ea,
    const int* __restrict__ row_ptr, const int* __restrict__ col_e,
    const int* __restrict__ col_s,
    const float* __restrict__ w1, const float* __restrict__ b1,
    const float* __restrict__ w2, const float* __restrict__ b2,
    const float* __restrict__ g, const float* __restrict__ be,
    float* __restrict__ h_out, int nrows) {
    __shared__ float w_lds[H * H];
    __shared__ float a_lds[32 * H];
    const int t = threadIdx.x;
    const int row0 = blockIdx.x * 32;

#pragma unroll
    for (int i = 0; i < 16; ++i)
        *(float4*)&w_lds[t * 4 + i * 1024] = *(const float4*)&w1[t * 4 + i * 1024];

    // gather phase: 8 nodes per pass (32 lanes x 4 floats per node), 4 passes
    const int j = (t & 31) * 4;
    for (int pass = 0; pass < 4; ++pass) {
        int r = pass * 8 + (t >> 5);
        int n = row0 + r;
        float ax = 0.f, ay = 0.f, az = 0.f, aw = 0.f;
        if (n < nrows) {
            int beg = row_ptr[n], end = row_ptr[n + 1];
            for (int p = beg; p < end; ++p) {
                int e = col_e[p];
                int s = col_s[p];
                float4 hv = *(const float4*)&h_in[s * H + j];
                float ex, ey, ez, ew;
                if constexpr (std::is_same<EA_T, float>::value) {
                    float4 ev = *(const float4*)(ea + (size_t)e * H + j);
                    ex = ev.x; ey = ev.y; ez = ev.z; ew = ev.w;
                } else {
                    const __half2* ep = (const __half2*)(ea + (size_t)e * H + j);
                    float2 e01 = __half22float2(ep[0]);
                    float2 e23 = __half22float2(ep[1]);
                    ex = e01.x; ey = e01.y; ez = e23.x; ew = e23.y;
                }
                ax += fmaxf(hv.x + ex, 0.f);
                ay += fmaxf(hv.y + ey, 0.f);
                az += fmaxf(hv.z + ez, 0.f);
                aw += fmaxf(hv.w + ew, 0.f);
            }
            float4 hn = *(const float4*)&h_in[n * H + j];
            ax += hn.x; ay += hn.y; az += hn.z; aw += hn.w;
        }
        float4 o = {ax, ay, az, aw};
        *(float4*)&a_lds[r * H + j] = o;
    }
    __syncthreads();

    const int tx = t & 31, ty = t >> 5;
    float acc[4][4] = {};
    mm_tile(a_lds, w_lds, tx, ty, acc);
    __syncthreads();   // everyone done reading w_lds(w1) & a_lds before overwrite

    // hid tile -> a_lds (relu(acc+b1)); stage w2 -> w_lds
    {
        float4 bb1 = *(const float4*)&b1[tx * 4];
#pragma unroll
        for (int rr = 0; rr < 4; ++rr) {
            float4 o;
            o.x = fmaxf(acc[rr][0] + bb1.x, 0.f);
            o.y = fmaxf(acc[rr][1] + bb1.y, 0.f);
            o.z = fmaxf(acc[rr][2] + bb1.z, 0.f);
            o.w = fmaxf(acc[rr][3] + bb1.w, 0.f);
            *(float4*)&a_lds[(ty * 4 + rr) * H + tx * 4] = o;
        }
#pragma unroll
        for (int i = 0; i < 16; ++i)
            *(float4*)&w_lds[t * 4 + i * 1024] = *(const float4*)&w2[t * 4 + i * 1024];
    }
    __syncthreads();

    float acc2[4][4] = {};
    mm_tile(a_lds, w_lds, tx, ty, acc2);

    float4 bb2 = *(const float4*)&b2[tx * 4];
#pragma unroll
    for (int rr = 0; rr < 4; ++rr) {
        int gr = row0 + ty * 4 + rr;
        bool ok = gr < nrows;
        float4 hres = {0.f, 0.f, 0.f, 0.f};
        if (ok) hres = *(const float4*)&h_in[(size_t)gr * H + tx * 4];
        float v0 = hres.x + fmaxf(acc2[rr][0] + bb2.x, 0.f);
        float v1 = hres.y + fmaxf(acc2[rr][1] + bb2.y, 0.f);
        float v2 = hres.z + fmaxf(acc2[rr][2] + bb2.z, 0.f);
        float v3 = hres.w + fmaxf(acc2[rr][3] + bb2.w, 0.f);
        float4 o = ln_vals(v0, v1, v2, v3, tx, g, be);
        if (ok) *(float4*)(h_out + (size_t)gr * H + tx * 4) = o;
    }
}

// ---------------- heads: GEMM-shaped ----------------
// W = [dh_w1 | sh_w1] (128x128). Lanes tx<16 hold disp-hidden cols, tx>=16
// stress-hidden cols. Tiny second layers = epilogue + 16-lane shuffle reduce.
__global__ __launch_bounds__(256) void heads_kernel(
    const float* __restrict__ h,
    const float* __restrict__ dh_w1, const float* __restrict__ dh_b1,
    const float* __restrict__ dh_w2, const float* __restrict__ dh_b2,
    const float* __restrict__ sh_w1, const float* __restrict__ sh_b1,
    const float* __restrict__ sh_w2, const float* __restrict__ sh_b2,
    const float* __restrict__ lds_scalar, float* __restrict__ out, int nrows) {
    __shared__ float w_lds[H * H];
    __shared__ float a_lds[32 * H];
    const int t = threadIdx.x;
    const int row0 = blockIdx.x * 32;
#pragma unroll
    for (int i = 0; i < 16; ++i) {
        int idx = t * 4 + i * 1024;
        int k = idx >> 7, c = idx & 127;
        const float* src = (c < 64) ? &dh_w1[k * 64 + c] : &sh_w1[k * 64 + (c - 64)];
        *(float4*)&w_lds[idx] = *(const float4*)src;
    }
#pragma unroll
    for (int i = 0; i < 4; ++i) {
        int idx = t * 4 + i * 1024;
        int rrow = row0 + (idx >> 7);
        float4 v = {0.f, 0.f, 0.f, 0.f};
        if (rrow < nrows) v = *(const float4*)&h[(size_t)row0 * H + idx];
        *(float4*)&a_lds[idx] = v;
    }
    __syncthreads();
    const int tx = t & 31, ty = t >> 5;
    float acc[4][4] = {};
    mm_tile(a_lds, w_lds, tx, ty, acc);

    const float ds = 0.001f + log1pf(expf(lds_scalar[0]));
    const bool isDisp = tx < 16;
    float b1v[4], w2v0[4], w2v1[4], w2v2[4];
#pragma unroll
    for (int cc = 0; cc < 4; ++cc) {
        int col = tx * 4 + cc;
        if (isDisp) {
            b1v[cc] = dh_b1[col];
            w2v0[cc] = dh_w2[col * 3 + 0];
            w2v1[cc] = dh_w2[col * 3 + 1];
            w2v2[cc] = dh_w2[col * 3 + 2];
        } else {
            b1v[cc] = sh_b1[col - 64];
            w2v0[cc] = sh_w2[col - 64];
            w2v1[cc] = 0.f;
            w2v2[cc] = 0.f;
        }
    }
#pragma unroll
    for (int rr = 0; rr < 4; ++rr) {
        int gr = row0 + ty * 4 + rr;
        float p0 = 0.f, p1 = 0.f, p2 = 0.f;
#pragma unroll
        for (int cc = 0; cc < 4; ++cc) {
            float hd = fmaxf(acc[rr][cc] + b1v[cc], 0.f);
            p0 = fmaf(hd, w2v0[cc], p0);
            p1 = fmaf(hd, w2v1[cc], p1);
            p2 = fmaf(hd, w2v2[cc], p2);
        }
#pragma unroll
        for (int m = 1; m < 16; m <<= 1) {
            p0 += __shfl_xor(p0, m, 64);
            p1 += __shfl_xor(p1, m, 64);
            p2 += __shfl_xor(p2, m, 64);
        }
        if ((tx & 15) == 0 && gr < nrows) {
            if (isDisp) {
                out[gr * 3 + 0] = (p0 + dh_b2[0]) * ds;
                out[gr * 3 + 1] = (p1 + dh_b2[1]) * ds;
                out[gr * 3 + 2] = (p2 + dh_b2[2]) * ds;
                if (gr == 0) out[250000] = ds;
            } else {
                float ls = fminf(fmaxf(p0 + sh_b2[0], 0.f), 30.f);
                float s = expf(ls);
                out[150000 + gr] = s;
                out[200000 + gr] = ls;
                out[250001 + gr] = 2.5e8f / (s + 1e-8f);
            }
        }
    }
}

// ---------------- launch ----------------
extern "C" void kernel_launch(void* const* d_in, const int* in_sizes, int n_in,
                              void* d_out, int out_size, void* d_ws, size_t ws_size,
                              hipStream_t stream) {
    // DIAGNOSTIC GUARD: if even the fp16-ea layout doesn't fit the workspace,
    // launch nothing. Validation then fails with a FINITE absmax (poisoned
    // d_out), which is a distinct signature from a device page-fault crash.
    // ws_size is constant per session -> branch is graph-capture-safe.
    if (ws_size < NEED16) return;

    const float* x         = (const float*)d_in[0];
    const float* edge_attr = (const float*)d_in[1];
    const int*   ei        = (const int*)d_in[2];
    const float* ne_w1 = (const float*)d_in[3];
    const float* ne_b1 = (const float*)d_in[4];
    const float* ne_w2 = (const float*)d_in[5];
    const float* ne_b2 = (const float*)d_in[6];
    const float* ne_g  = (const float*)d_in[7];
    const float* ne_be = (const float*)d_in[8];
    const float* ee_w1 = (const float*)d_in[9];
    const float* ee_b1 = (const float*)d_in[10];
    const float* ee_w2 = (const float*)d_in[11];
    const float* ee_b2 = (const float*)d_in[12];
    const float* ee_g  = (const float*)d_in[13];
    const float* ee_be = (const float*)d_in[14];
    const float* conv_w1 = (const float*)d_in[15];
    const float* conv_b1 = (const float*)d_in[16];
    const float* conv_w2 = (const float*)d_in[17];
    const float* conv_b2 = (const float*)d_in[18];
    const float* pn_g  = (const float*)d_in[19];
    const float* pn_be = (const float*)d_in[20];
    const float* dh_w1 = (const float*)d_in[21];
    const float* dh_b1 = (const float*)d_in[22];
    const float* dh_w2 = (const float*)d_in[23];
    const float* dh_b2 = (const float*)d_in[24];
    const float* sh_w1 = (const float*)d_in[25];
    const float* sh_b1 = (const float*)d_in[26];
    const float* sh_w2 = (const float*)d_in[27];
    const float* sh_b2 = (const float*)d_in[28];
    const float* ldsc  = (const float*)d_in[29];

    float* ws = (float*)d_ws;
    float* h0 = ws;
    float* h1 = ws + W_H1;
    int* row_ptr = (int*)(ws + W_RP);
    int* cursor  = (int*)(ws + W_CUR);
    int* col_e   = (int*)(ws + W_CE);
    int* col_s   = (int*)(ws + W_CS);
    void* ea     = (void*)(ws + W_EA);
    float* out = (float*)d_out;

    const bool use32 = ws_size >= NEED32;   // constant per session -> capture-safe

    // CSR build (rebuilt every call; ws is re-poisoned before every call)
    hipMemsetAsync(cursor, 0, N_NODES * sizeof(int), stream);
    count_kernel<<<(N_EDGES + 255) / 256, 256, 0, stream>>>(ei, cursor);
    scan_kernel<<<1, 1024, 0, stream>>>(cursor, row_ptr);
    fill_kernel<<<(N_EDGES + 255) / 256, 256, 0, stream>>>(ei, cursor, col_e, col_s);

    // node encoder -> h0
    encoder_kernel<5, float><<<(N_NODES + 31) / 32, 256, 0, stream>>>(
        x, ne_w1, ne_b1, ne_w2, ne_b2, ne_g, ne_be, h0, N_NODES);

    if (use32) {
        encoder_kernel<6, float><<<N_EDGES / 32, 256, 0, stream>>>(
            edge_attr, ee_w1, ee_b1, ee_w2, ee_b2, ee_g, ee_be, (float*)ea, N_EDGES);
        float* hin = h0; float* hout = h1;
        for (int l = 0; l < 3; ++l) {
            conv_kernel<float><<<(N_NODES + 31) / 32, 256, 0, stream>>>(
                hin, (const float*)ea, row_ptr, col_e, col_s,
                conv_w1 + (size_t)l * H * H, conv_b1 + l * H,
                conv_w2 + (size_t)l * H * H, conv_b2 + l * H,
                pn_g + l * H, pn_be + l * H, hout, N_NODES);
            float* tmp = hin; hin = hout; hout = tmp;
        }
    } else {
        encoder_kernel<6, __half><<<N_EDGES / 32, 256, 0, stream>>>(
            edge_attr, ee_w1, ee_b1, ee_w2, ee_b2, ee_g, ee_be, (__half*)ea, N_EDGES);
        float* hin = h0; float* hout = h1;
        for (int l = 0; l < 3; ++l) {
            conv_kernel<__half><<<(N_NODES + 31) / 32, 256, 0, stream>>>(
                hin, (const __half*)ea, row_ptr, col_e, col_s,
                conv_w1 + (size_t)l * H * H, conv_b1 + l * H,
                conv_w2 + (size_t)l * H * H, conv_b2 + l * H,
                pn_g + l * H, pn_be + l * H, hout, N_NODES);
            float* tmp = hin; hin = hout; hout = tmp;
        }
    }

    // after 3 ping-pong layers the final h is h1
    heads_kernel<<<(N_NODES + 31) / 32, 256, 0, stream>>>(
        h1, dh_w1, dh_b1, dh_w2, dh_b2, sh_w1, sh_b1, sh_w2, sh_b2, ldsc, out, N_NODES);
}

// Round 9
// 1154.077 us; speedup vs baseline: 1.7810x; 1.7810x over previous
//
#include <hip/hip_runtime.h>
#include <hip/hip_bf16.h>
#include <hip/hip_fp16.h>
#include <type_traits>

#define N_NODES 50000
#define N_EDGES 600000
#define H 128

// ---------------- workspace layout (word offsets), ea LAST --------
constexpr size_t W_H1  = 6400000;
constexpr size_t W_RP  = 12800000;
constexpr size_t W_CUR = 12850004;
constexpr size_t W_CE  = 12900004;
constexpr size_t W_CS  = 13500004;
constexpr size_t W_EA  = 14100004;                       // *4B (16B aligned)
constexpr size_t NEED32 = (W_EA + (size_t)N_EDGES * H) * 4;        // 363.6 MB
constexpr size_t NEED16 = (W_EA + (size_t)N_EDGES * H / 2) * 4;    // 210.0 MB

// ---------------- CSR build ----------------
__global__ void count_kernel(const int* __restrict__ ei, int* __restrict__ cnt) {
    int e = blockIdx.x * blockDim.x + threadIdx.x;
    if (e < N_EDGES) atomicAdd(&cnt[ei[N_EDGES + e]], 1);
}

__global__ void scan_kernel(int* __restrict__ cursor, int* __restrict__ row_ptr) {
    __shared__ int wsum[16];
    __shared__ int wexc[16];
    __shared__ int s_total;
    const int t = threadIdx.x;
    const int lane = t & 63, wid = t >> 6;
    int carry = 0;
    if (t == 0) row_ptr[0] = 0;
    for (int base = 0; base < N_NODES; base += 1024) {
        int i = base + t;
        int v = (i < N_NODES) ? cursor[i] : 0;
        int x = v;
#pragma unroll
        for (int off = 1; off < 64; off <<= 1) {
            int y = __shfl_up(x, off, 64);
            if (lane >= off) x += y;
        }
        if (lane == 63) wsum[wid] = x;
        __syncthreads();
        if (wid == 0 && lane < 16) {
            int w = wsum[lane];
            int xs = w;
#pragma unroll
            for (int off = 1; off < 16; off <<= 1) {
                int y = __shfl_up(xs, off, 64);
                if (lane >= off) xs += y;
            }
            wexc[lane] = xs - w;
            if (lane == 15) s_total = xs;
        }
        __syncthreads();
        int incl = carry + wexc[wid] + x;
        if (i < N_NODES) {
            cursor[i] = incl - v;
            row_ptr[i + 1] = incl;
        }
        carry += s_total;
        __syncthreads();
    }
}

__global__ void fill_kernel(const int* __restrict__ ei, int* __restrict__ cursor,
                            int* __restrict__ col_e, int* __restrict__ col_s) {
    int e = blockIdx.x * blockDim.x + threadIdx.x;
    if (e < N_EDGES) {
        int d = ei[N_EDGES + e];
        int pos = atomicAdd(&cursor[d], 1);
        col_e[pos] = e;
        col_s[pos] = ei[e];
    }
}

// ---------------- K-split GEMM core: 32 rows x 128 cols over k in [k0,k0+64) ----------
// a_lds: [32][128] full-K tile; w_lds: [64][128] half-K weight slice.
// LDS = 16KB + 32KB = 48KB -> 3 blocks/CU (vs 80KB -> 1) [round-7 occupancy fix]
__device__ __forceinline__ void mm_half(const float* __restrict__ a_lds,
                                        const float* __restrict__ w_lds,
                                        int tx, int ty, int k0, float acc[4][4]) {
#pragma unroll 8
    for (int k = 0; k < 64; k += 4) {
        float4 av[4], wv[4];
#pragma unroll
        for (int rr = 0; rr < 4; ++rr)
            av[rr] = *(const float4*)&a_lds[(ty * 4 + rr) * H + k0 + k];
#pragma unroll
        for (int kk = 0; kk < 4; ++kk)
            wv[kk] = *(const float4*)&w_lds[(k + kk) * H + tx * 4];
#pragma unroll
        for (int rr = 0; rr < 4; ++rr) {
#pragma unroll
            for (int kk = 0; kk < 4; ++kk) {
                float a = ((const float*)&av[rr])[kk];
                acc[rr][0] = fmaf(a, ((const float*)&wv[kk])[0], acc[rr][0]);
                acc[rr][1] = fmaf(a, ((const float*)&wv[kk])[1], acc[rr][1]);
                acc[rr][2] = fmaf(a, ((const float*)&wv[kk])[2], acc[rr][2]);
                acc[rr][3] = fmaf(a, ((const float*)&wv[kk])[3], acc[rr][3]);
            }
        }
    }
}

// stage 64 rows of a [128-col] weight matrix into w_lds (8 float4/thread)
__device__ __forceinline__ void stage_whalf(const float* __restrict__ wsrc,
                                            float* __restrict__ w_lds, int t) {
#pragma unroll
    for (int i = 0; i < 8; ++i)
        *(float4*)&w_lds[t * 4 + i * 1024] = *(const float4*)&wsrc[t * 4 + i * 1024];
}

// LayerNorm over one row spread across a 32-lane tx group (4 vals/lane).
// xor masks 1..16 keep lanes within their 32-lane half; call UNCONDITIONALLY.
__device__ __forceinline__ float4 ln_vals(float v0, float v1, float v2, float v3,
                                          int tx, const float* __restrict__ g,
                                          const float* __restrict__ be) {
    float sum = v0 + v1 + v2 + v3;
    float sq = v0 * v0 + v1 * v1 + v2 * v2 + v3 * v3;
#pragma unroll
    for (int m = 1; m < 32; m <<= 1) {
        sum += __shfl_xor(sum, m, 64);
        sq  += __shfl_xor(sq, m, 64);
    }
    float mean = sum * 0.0078125f;
    float var = sq * 0.0078125f - mean * mean;
    float rstd = rsqrtf(var + 1e-5f);
    float4 gv = *(const float4*)&g[tx * 4];
    float4 bv = *(const float4*)&be[tx * 4];
    float4 o;
    o.x = (v0 - mean) * rstd * gv.x + bv.x;
    o.y = (v1 - mean) * rstd * gv.y + bv.y;
    o.z = (v2 - mean) * rstd * gv.z + bv.z;
    o.w = (v3 - mean) * rstd * gv.w + bv.w;
    return o;
}

// ---------------- encoder: OUT = LN(relu(in@w1+b1)@w2+b2) ----------------
template <int IN_DIM, typename OUT_T>
__global__ __launch_bounds__(256, 3) void encoder_kernel(
    const float* __restrict__ in, const float* __restrict__ w1,
    const float* __restrict__ b1, const float* __restrict__ w2,
    const float* __restrict__ b2, const float* __restrict__ g,
    const float* __restrict__ be, OUT_T* __restrict__ out,
    int nrows) {
    __shared__ float w_lds[64 * H];
    __shared__ float a_lds[32 * H];
    const int t = threadIdx.x;
    const int row0 = blockIdx.x * 32;

    stage_whalf(w2, w_lds, t);          // k = 0..63

    // hidden stage: column-per-thread (conflict-free LDS writes)
    {
        const int c = t & 127;
        const int rh = (t >> 7) * 16;
        const float bb1 = b1[c];
        float w1r[IN_DIM];
#pragma unroll
        for (int i = 0; i < IN_DIM; ++i)
            w1r[i] = w1[i * H + c];
#pragma unroll 4
        for (int rr = 0; rr < 16; ++rr) {
            int r = rh + rr;
            int grow = row0 + r;
            float acc = bb1;
            if (grow < nrows) {
#pragma unroll
                for (int i = 0; i < IN_DIM; ++i)
                    acc = fmaf(in[(size_t)grow * IN_DIM + i], w1r[i], acc);
            }
            a_lds[r * H + c] = fmaxf(acc, 0.f);
        }
    }
    __syncthreads();

    const int tx = t & 31, ty = t >> 5;
    float acc[4][4] = {};
    mm_half(a_lds, w_lds, tx, ty, 0, acc);
    __syncthreads();
    stage_whalf(w2 + 64 * H, w_lds, t); // k = 64..127
    __syncthreads();
    mm_half(a_lds, w_lds, tx, ty, 64, acc);

    float4 bb = *(const float4*)&b2[tx * 4];
#pragma unroll
    for (int rr = 0; rr < 4; ++rr) {
        int gr = row0 + ty * 4 + rr;
        float4 o = ln_vals(acc[rr][0] + bb.x, acc[rr][1] + bb.y,
                           acc[rr][2] + bb.z, acc[rr][3] + bb.w, tx, g, be);
        if (gr < nrows) {
            if constexpr (std::is_same<OUT_T, float>::value) {
                *(float4*)(out + (size_t)gr * H + tx * 4) = o;
            } else {
                __half2* dp = (__half2*)(out + (size_t)gr * H + tx * 4);
                dp[0] = __floats2half2_rn(o.x, o.y);
                dp[1] = __floats2half2_rn(o.z, o.w);
            }
        }
    }
}

// ---------------- fused GINEConv layer ----------------
// a = h_in + sum_in relu(h_in[src]+ea[e]);  hid = relu(a@w1+b1) (in LDS)
// h_out = LN(h_in + relu(hid@w2+b2))
template <typename EA_T>
__global__ __launch_bounds__(256, 3) void conv_kernel(
    const float* __restrict__ h_in, const EA_T* __restrict__ ea,
    const int* __restrict__ row_ptr, const int* __restrict__ col_e,
    const int* __restrict__ col_s,
    const float* __restrict__ w1, const float* __restrict__ b1,
    const float* __restrict__ w2, const float* __restrict__ b2,
    const float* __restrict__ g, const float* __restrict__ be,
    float* __restrict__ h_out, int nrows) {
    __shared__ float w_lds[64 * H];
    __shared__ float a_lds[32 * H];
    const int t = threadIdx.x;
    const int row0 = blockIdx.x * 32;

    stage_whalf(w1, w_lds, t);          // w1 k=0..63

    // gather phase: 8 nodes per pass (32 lanes x 4 floats per node), 4 passes
    const int j = (t & 31) * 4;
    for (int pass = 0; pass < 4; ++pass) {
        int r = pass * 8 + (t >> 5);
        int n = row0 + r;
        float ax = 0.f, ay = 0.f, az = 0.f, aw = 0.f;
        if (n < nrows) {
            int beg = row_ptr[n], end = row_ptr[n + 1];
            for (int p = beg; p < end; ++p) {
                int e = col_e[p];
                int s = col_s[p];
                float4 hv = *(const float4*)&h_in[s * H + j];
                float ex, ey, ez, ew;
                if constexpr (std::is_same<EA_T, float>::value) {
                    float4 ev = *(const float4*)(ea + (size_t)e * H + j);
                    ex = ev.x; ey = ev.y; ez = ev.z; ew = ev.w;
                } else {
                    const __half2* ep = (const __half2*)(ea + (size_t)e * H + j);
                    float2 e01 = __half22float2(ep[0]);
                    float2 e23 = __half22float2(ep[1]);
                    ex = e01.x; ey = e01.y; ez = e23.x; ew = e23.y;
                }
                ax += fmaxf(hv.x + ex, 0.f);
                ay += fmaxf(hv.y + ey, 0.f);
                az += fmaxf(hv.z + ez, 0.f);
                aw += fmaxf(hv.w + ew, 0.f);
            }
            float4 hn = *(const float4*)&h_in[n * H + j];
            ax += hn.x; ay += hn.y; az += hn.z; aw += hn.w;
        }
        float4 o = {ax, ay, az, aw};
        *(float4*)&a_lds[r * H + j] = o;
    }
    __syncthreads();

    const int tx = t & 31, ty = t >> 5;
    float acc[4][4] = {};
    mm_half(a_lds, w_lds, tx, ty, 0, acc);
    __syncthreads();
    stage_whalf(w1 + 64 * H, w_lds, t); // w1 k=64..127
    __syncthreads();
    mm_half(a_lds, w_lds, tx, ty, 64, acc);
    __syncthreads();   // all reads of a_lds done before hid overwrite

    // hid tile -> a_lds (relu(acc+b1)); stage w2 half0
    {
        float4 bb1 = *(const float4*)&b1[tx * 4];
#pragma unroll
        for (int rr = 0; rr < 4; ++rr) {
            float4 o;
            o.x = fmaxf(acc[rr][0] + bb1.x, 0.f);
            o.y = fmaxf(acc[rr][1] + bb1.y, 0.f);
            o.z = fmaxf(acc[rr][2] + bb1.z, 0.f);
            o.w = fmaxf(acc[rr][3] + bb1.w, 0.f);
            *(float4*)&a_lds[(ty * 4 + rr) * H + tx * 4] = o;
        }
        stage_whalf(w2, w_lds, t);      // w2 k=0..63
    }
    __syncthreads();

    float acc2[4][4] = {};
    mm_half(a_lds, w_lds, tx, ty, 0, acc2);
    __syncthreads();
    stage_whalf(w2 + 64 * H, w_lds, t); // w2 k=64..127
    __syncthreads();
    mm_half(a_lds, w_lds, tx, ty, 64, acc2);

    float4 bb2 = *(const float4*)&b2[tx * 4];
#pragma unroll
    for (int rr = 0; rr < 4; ++rr) {
        int gr = row0 + ty * 4 + rr;
        bool ok = gr < nrows;
        float4 hres = {0.f, 0.f, 0.f, 0.f};
        if (ok) hres = *(const float4*)&h_in[(size_t)gr * H + tx * 4];
        float v0 = hres.x + fmaxf(acc2[rr][0] + bb2.x, 0.f);
        float v1 = hres.y + fmaxf(acc2[rr][1] + bb2.y, 0.f);
        float v2 = hres.z + fmaxf(acc2[rr][2] + bb2.z, 0.f);
        float v3 = hres.w + fmaxf(acc2[rr][3] + bb2.w, 0.f);
        float4 o = ln_vals(v0, v1, v2, v3, tx, g, be);
        if (ok) *(float4*)(h_out + (size_t)gr * H + tx * 4) = o;
    }
}

// ---------------- heads: GEMM-shaped, K-split ----------------
// W = [dh_w1 | sh_w1] (128x128). Lanes tx<16 -> disp cols, tx>=16 -> stress.
__global__ __launch_bounds__(256, 3) void heads_kernel(
    const float* __restrict__ h,
    const float* __restrict__ dh_w1, const float* __restrict__ dh_b1,
    const float* __restrict__ dh_w2, const float* __restrict__ dh_b2,
    const float* __restrict__ sh_w1, const float* __restrict__ sh_b1,
    const float* __restrict__ sh_w2, const float* __restrict__ sh_b2,
    const float* __restrict__ lds_scalar, float* __restrict__ out, int nrows) {
    __shared__ float w_lds[64 * H];
    __shared__ float a_lds[32 * H];
    const int t = threadIdx.x;
    const int row0 = blockIdx.x * 32;

    // stage combined-W rows k=k0..k0+63
    auto stage_heads = [&](int k0) {
#pragma unroll
        for (int i = 0; i < 8; ++i) {
            int idx = t * 4 + i * 1024;
            int kl = idx >> 7, c = idx & 127;
            const float* src = (c < 64) ? &dh_w1[(k0 + kl) * 64 + c]
                                        : &sh_w1[(k0 + kl) * 64 + (c - 64)];
            *(float4*)&w_lds[idx] = *(const float4*)src;
        }
    };
    stage_heads(0);
#pragma unroll
    for (int i = 0; i < 4; ++i) {
        int idx = t * 4 + i * 1024;
        int rrow = row0 + (idx >> 7);
        float4 v = {0.f, 0.f, 0.f, 0.f};
        if (rrow < nrows) v = *(const float4*)&h[(size_t)row0 * H + idx];
        *(float4*)&a_lds[idx] = v;
    }
    __syncthreads();
    const int tx = t & 31, ty = t >> 5;
    float acc[4][4] = {};
    mm_half(a_lds, w_lds, tx, ty, 0, acc);
    __syncthreads();
    stage_heads(64);
    __syncthreads();
    mm_half(a_lds, w_lds, tx, ty, 64, acc);

    const float ds = 0.001f + log1pf(expf(lds_scalar[0]));
    const bool isDisp = tx < 16;
    float b1v[4], w2v0[4], w2v1[4], w2v2[4];
#pragma unroll
    for (int cc = 0; cc < 4; ++cc) {
        int col = tx * 4 + cc;
        if (isDisp) {
            b1v[cc] = dh_b1[col];
            w2v0[cc] = dh_w2[col * 3 + 0];
            w2v1[cc] = dh_w2[col * 3 + 1];
            w2v2[cc] = dh_w2[col * 3 + 2];
        } else {
            b1v[cc] = sh_b1[col - 64];
            w2v0[cc] = sh_w2[col - 64];
            w2v1[cc] = 0.f;
            w2v2[cc] = 0.f;
        }
    }
#pragma unroll
    for (int rr = 0; rr < 4; ++rr) {
        int gr = row0 + ty * 4 + rr;
        float p0 = 0.f, p1 = 0.f, p2 = 0.f;
#pragma unroll
        for (int cc = 0; cc < 4; ++cc) {
            float hd = fmaxf(acc[rr][cc] + b1v[cc], 0.f);
            p0 = fmaf(hd, w2v0[cc], p0);
            p1 = fmaf(hd, w2v1[cc], p1);
            p2 = fmaf(hd, w2v2[cc], p2);
        }
#pragma unroll
        for (int m = 1; m < 16; m <<= 1) {
            p0 += __shfl_xor(p0, m, 64);
            p1 += __shfl_xor(p1, m, 64);
            p2 += __shfl_xor(p2, m, 64);
        }
        if ((tx & 15) == 0 && gr < nrows) {
            if (isDisp) {
                out[gr * 3 + 0] = (p0 + dh_b2[0]) * ds;
                out[gr * 3 + 1] = (p1 + dh_b2[1]) * ds;
                out[gr * 3 + 2] = (p2 + dh_b2[2]) * ds;
                if (gr == 0) out[250000] = ds;
            } else {
                float ls = fminf(fmaxf(p0 + sh_b2[0], 0.f), 30.f);
                float s = expf(ls);
                out[150000 + gr] = s;
                out[200000 + gr] = ls;
                out[250001 + gr] = 2.5e8f / (s + 1e-8f);
            }
        }
    }
}

// ---------------- launch ----------------
extern "C" void kernel_launch(void* const* d_in, const int* in_sizes, int n_in,
                              void* d_out, int out_size, void* d_ws, size_t ws_size,
                              hipStream_t stream) {
    if (ws_size < NEED16) return;  // diagnostic guard (capture-safe: ws_size const)

    const float* x         = (const float*)d_in[0];
    const float* edge_attr = (const float*)d_in[1];
    const int*   ei        = (const int*)d_in[2];
    const float* ne_w1 = (const float*)d_in[3];
    const float* ne_b1 = (const float*)d_in[4];
    const float* ne_w2 = (const float*)d_in[5];
    const float* ne_b2 = (const float*)d_in[6];
    const float* ne_g  = (const float*)d_in[7];
    const float* ne_be = (const float*)d_in[8];
    const float* ee_w1 = (const float*)d_in[9];
    const float* ee_b1 = (const float*)d_in[10];
    const float* ee_w2 = (const float*)d_in[11];
    const float* ee_b2 = (const float*)d_in[12];
    const float* ee_g  = (const float*)d_in[13];
    const float* ee_be = (const float*)d_in[14];
    const float* conv_w1 = (const float*)d_in[15];
    const float* conv_b1 = (const float*)d_in[16];
    const float* conv_w2 = (const float*)d_in[17];
    const float* conv_b2 = (const float*)d_in[18];
    const float* pn_g  = (const float*)d_in[19];
    const float* pn_be = (const float*)d_in[20];
    const float* dh_w1 = (const float*)d_in[21];
    const float* dh_b1 = (const float*)d_in[22];
    const float* dh_w2 = (const float*)d_in[23];
    const float* dh_b2 = (const float*)d_in[24];
    const float* sh_w1 = (const float*)d_in[25];
    const float* sh_b1 = (const float*)d_in[26];
    const float* sh_w2 = (const float*)d_in[27];
    const float* sh_b2 = (const float*)d_in[28];
    const float* ldsc  = (const float*)d_in[29];

    float* ws = (float*)d_ws;
    float* h0 = ws;
    float* h1 = ws + W_H1;
    int* row_ptr = (int*)(ws + W_RP);
    int* cursor  = (int*)(ws + W_CUR);
    int* col_e   = (int*)(ws + W_CE);
    int* col_s   = (int*)(ws + W_CS);
    void* ea     = (void*)(ws + W_EA);
    float* out = (float*)d_out;

    const bool use32 = ws_size >= NEED32;

    // CSR build
    hipMemsetAsync(cursor, 0, N_NODES * sizeof(int), stream);
    count_kernel<<<(N_EDGES + 255) / 256, 256, 0, stream>>>(ei, cursor);
    scan_kernel<<<1, 1024, 0, stream>>>(cursor, row_ptr);
    fill_kernel<<<(N_EDGES + 255) / 256, 256, 0, stream>>>(ei, cursor, col_e, col_s);

    // node encoder -> h0
    encoder_kernel<5, float><<<(N_NODES + 31) / 32, 256, 0, stream>>>(
        x, ne_w1, ne_b1, ne_w2, ne_b2, ne_g, ne_be, h0, N_NODES);

    if (use32) {
        encoder_kernel<6, float><<<N_EDGES / 32, 256, 0, stream>>>(
            edge_attr, ee_w1, ee_b1, ee_w2, ee_b2, ee_g, ee_be, (float*)ea, N_EDGES);
        float* hin = h0; float* hout = h1;
        for (int l = 0; l < 3; ++l) {
            conv_kernel<float><<<(N_NODES + 31) / 32, 256, 0, stream>>>(
                hin, (const float*)ea, row_ptr, col_e, col_s,
                conv_w1 + (size_t)l * H * H, conv_b1 + l * H,
                conv_w2 + (size_t)l * H * H, conv_b2 + l * H,
                pn_g + l * H, pn_be + l * H, hout, N_NODES);
            float* tmp = hin; hin = hout; hout = tmp;
        }
    } else {
        encoder_kernel<6, __half><<<N_EDGES / 32, 256, 0, stream>>>(
            edge_attr, ee_w1, ee_b1, ee_w2, ee_b2, ee_g, ee_be, (__half*)ea, N_EDGES);
        float* hin = h0; float* hout = h1;
        for (int l = 0; l < 3; ++l) {
            conv_kernel<__half><<<(N_NODES + 31) / 32, 256, 0, stream>>>(
                hin, (const __half*)ea, row_ptr, col_e, col_s,
                conv_w1 + (size_t)l * H * H, conv_b1 + l * H,
                conv_w2 + (size_t)l * H * H, conv_b2 + l * H,
                pn_g + l * H, pn_be + l * H, hout, N_NODES);
            float* tmp = hin; hin = hout; hout = tmp;
        }
    }

    // after 3 ping-pong layers the final h is h1
    heads_kernel<<<(N_NODES + 31) / 32, 256, 0, stream>>>(
        h1, dh_w1, dh_b1, dh_w2, dh_b2, sh_w1, sh_b1, sh_w2, sh_b2, ldsc, out, N_NODES);
}